// Round 10
// baseline (113.546 us; speedup 1.0000x reference)
//
#include <hip/hip_runtime.h>
#include <math.h>

// ROUND 10 = MEASUREMENT ROUND. R9 pipeline verbatim, but grid=64 with a 4-deep
// bh loop per block so the kernel duration (~4x) re-enters rocprof's top-5 and
// we finally get counters (VGPR/spill, VALUBusy, LDS conflicts, FETCH/WRITE).
// Expected slower than R9 overall; this buys the attribution data.

#define B 2
#define C 128
#define H 128
#define W 256
#define K 20
#define HW (H * W)
#define SO_STRIDE 260

typedef float f32x4 __attribute__((ext_vector_type(4)));
typedef short bf16x8 __attribute__((ext_vector_type(8)));

__device__ __forceinline__ unsigned f2bf_bits(float x) {
    unsigned u = __float_as_uint(x);
    return (u + 0x7FFFu + ((u >> 16) & 1u)) >> 16;
}
__device__ __forceinline__ float bf_to_f(unsigned bits) {
    return __uint_as_float(bits << 16);
}

__global__ __launch_bounds__(1024) void isomax_fused_diag(
    const float* __restrict__ feats, const float* __restrict__ protos,
    const float* __restrict__ dscale, float* __restrict__ out)
{
    __shared__ __align__(16) unsigned s_u32[C * 128];   // 64 KB bf16 tile
    __shared__ float s_rp[32];
    __shared__ float s_pp[32];
    __shared__ float s_S[W];
    __shared__ __align__(16) float s_o[K * SO_STRIDE];

    const int tid  = threadIdx.x;
    const int wave = tid >> 6, lane = tid & 63;
    const int quad = lane >> 4, l16 = lane & 15;
    const int m0   = wave * 16;
    const int bh0  = blockIdx.x * 4;

    // ---- Phase P once (bh-independent), R9-verbatim ----
    {
        const int k0 = wave;
        const int k1 = 16 + (wave & 3);
        const float pa0 = protos[k0 * C + lane], pb0 = protos[k0 * C + lane + 64];
        const float pa1 = protos[k1 * C + lane], pb1 = protos[k1 * C + lane + 64];
        float ss0 = fmaf(pa0, pa0, pb0 * pb0);
        float ss1 = fmaf(pa1, pa1, pb1 * pb1);
        #pragma unroll
        for (int off = 32; off > 0; off >>= 1) {
            ss0 += __shfl_xor(ss0, off, 64);
            ss1 += __shfl_xor(ss1, off, 64);
        }
        const float rp0 = 1.0f / fmaxf(sqrtf(ss0), 1e-12f);
        const float rp1 = 1.0f / fmaxf(sqrtf(ss1), 1e-12f);
        const float q00 = bf_to_f(f2bf_bits(pa0 * rp0));
        const float q01 = bf_to_f(f2bf_bits(pb0 * rp0));
        const float q10 = bf_to_f(f2bf_bits(pa1 * rp1));
        const float q11 = bf_to_f(f2bf_bits(pb1 * rp1));
        float s20 = fmaf(q00, q00, q01 * q01);
        float s21 = fmaf(q10, q10, q11 * q11);
        #pragma unroll
        for (int off = 32; off > 0; off >>= 1) {
            s20 += __shfl_xor(s20, off, 64);
            s21 += __shfl_xor(s21, off, 64);
        }
        if (lane == 0) {
            s_rp[k0] = rp0; s_pp[k0] = s20;
            if (wave < 4) { s_rp[k1] = rp1; s_pp[k1] = s21; }
        }
    }

    #define PROC_GROUP(fR, c0)                                                     \
    {                                                                              \
        float ss[4];                                                               \
        _Pragma("unroll")                                                          \
        for (int r = 0; r < 4; ++r) {                                              \
            const float4 v = fR[r];                                                \
            ss[r] = fmaf(v.x, v.x, fmaf(v.y, v.y, fmaf(v.z, v.z, v.w * v.w)));     \
        }                                                                          \
        _Pragma("unroll")                                                          \
        for (int off = 32; off > 0; off >>= 1) {                                   \
            _Pragma("unroll")                                                      \
            for (int r = 0; r < 4; ++r) ss[r] += __shfl_xor(ss[r], off, 64);       \
        }                                                                          \
        _Pragma("unroll")                                                          \
        for (int r = 0; r < 4; ++r) {                                              \
            const float rn = 1.0f / fmaxf(sqrtf(ss[r]), 1e-12f);                   \
            const float4 v = fR[r];                                                \
            const unsigned lo = f2bf_bits(v.x * rn) | (f2bf_bits(v.y * rn) << 16); \
            const unsigned hi = f2bf_bits(v.z * rn) | (f2bf_bits(v.w * rn) << 16); \
            const int c = (c0) + r;                                                \
            const int word = c * 128 + ((lane * 2) ^ (((c >> 3) & 3) << 3));       \
            uint2 pk; pk.x = lo; pk.y = hi;                                        \
            *(uint2*)&s_u32[word] = pk;                                            \
        }                                                                          \
    }

    for (int it = 0; it < 4; ++it) {
        const int bh = bh0 + it;
        const int b  = bh >> 7, h = bh & 127;
        const float* fb = feats + (size_t)b * C * HW + h * W;

        // ---- Stage: load 8 rows/wave (two batched groups), norm, write tile ----
        const int cA = wave * 8;
        float4 fA[4];
        #pragma unroll
        for (int r = 0; r < 4; ++r)
            fA[r] = ((const float4*)(fb + (size_t)(cA + r) * HW))[lane];
        const int cB = cA + 4;
        float4 fB[4];
        #pragma unroll
        for (int r = 0; r < 4; ++r)
            fB[r] = ((const float4*)(fb + (size_t)(cB + r) * HW))[lane];

        PROC_GROUP(fA, cA)
        PROC_GROUP(fB, cB)
        __syncthreads();   // tile ready (it==0: also s_rp/s_pp)

        // ---- B-fragments (R9-verbatim, rebuilt per iteration) ----
        bf16x8 bfrag[4][2];
        #pragma unroll
        for (int t = 0; t < 2; ++t) {
            const int k = t * 16 + l16;
            const float rp = (k < K) ? s_rp[k] : 0.0f;
            #pragma unroll
            for (int ch = 0; ch < 4; ++ch) {
                bf16x8 f = {0, 0, 0, 0, 0, 0, 0, 0};
                if (k < K) {
                    const float* pr = protos + k * C + ch * 32 + quad * 8;
                    const float4 pa = *(const float4*)(pr);
                    const float4 pb = *(const float4*)(pr + 4);
                    f[0] = (short)f2bf_bits(pa.x * rp);
                    f[1] = (short)f2bf_bits(pa.y * rp);
                    f[2] = (short)f2bf_bits(pa.z * rp);
                    f[3] = (short)f2bf_bits(pa.w * rp);
                    f[4] = (short)f2bf_bits(pb.x * rp);
                    f[5] = (short)f2bf_bits(pb.y * rp);
                    f[6] = (short)f2bf_bits(pb.z * rp);
                    f[7] = (short)f2bf_bits(pb.w * rp);
                }
                bfrag[ch][t] = f;
            }
        }

        // ---- MFMA (R9-verbatim addressing) ----
        f32x4 acc0 = {0.f, 0.f, 0.f, 0.f}, acc1 = {0.f, 0.f, 0.f, 0.f};
        float Sp = 0.f;
        const int wadrw = ((m0 + l16) >> 1) ^ (quad << 3);
        const unsigned sel = (unsigned)(l16 & 1);
        #pragma unroll
        for (int ch = 0; ch < 4; ++ch) {
            bf16x8 af;
            #pragma unroll
            for (int j = 0; j < 8; ++j) {
                const int rowi = ch * 32 + quad * 8 + j;
                const unsigned v = s_u32[rowi * 128 + wadrw];
                af[j] = (short)(sel ? (v >> 16) : v);
                const float ur = __uint_as_float(sel ? (v & 0xffff0000u) : (v << 16));
                Sp = fmaf(ur, ur, Sp);
            }
            acc0 = __builtin_amdgcn_mfma_f32_16x16x32_bf16(af, bfrag[ch][0], acc0, 0, 0, 0);
            acc1 = __builtin_amdgcn_mfma_f32_16x16x32_bf16(af, bfrag[ch][1], acc1, 0, 0, 0);
        }

        // ---- S[w] ----
        Sp += __shfl_xor(Sp, 16, 64);
        Sp += __shfl_xor(Sp, 32, 64);
        if (lane < 16) s_S[m0 + lane] = Sp;
        __syncthreads();

        // ---- Epilogue ----
        const float scale = fabsf(dscale[0]);
        const float pcol0 = s_pp[l16];
        const float pcol1 = (l16 < 4) ? s_pp[16 + l16] : 0.0f;
        #pragma unroll
        for (int r = 0; r < 4; ++r) {
            const int wl = m0 + quad * 4 + r;
            const float Sm = s_S[wl];
            const float d20 = fmaxf(Sm + pcol0 - 2.0f * acc0[r], 0.f);
            s_o[l16 * SO_STRIDE + wl] = -scale * sqrtf(d20);
            if (l16 < 4) {
                const float d21 = fmaxf(Sm + pcol1 - 2.0f * acc1[r], 0.f);
                s_o[(16 + l16) * SO_STRIDE + wl] = -scale * sqrtf(d21);
            }
        }
        __syncthreads();

        // ---- Store 20 k-rows x 256 w ----
        for (int i = tid; i < K * (W / 4); i += 1024) {
            const int k = i >> 6, g = i & 63;
            const float4 v = *(const float4*)&s_o[k * SO_STRIDE + g * 4];
            *(float4*)(out + ((size_t)(b * K + k)) * HW + h * W + g * 4) = v;
        }
        // next iteration's s_u32 writes are safe: all s_u32 reads happened before
        // the s_S barrier of this iteration; s_o rewrites are fenced by the
        // stage-end barrier of the next iteration... (store reads s_o, next
        // epilogue writes s_o only after two barriers) 
        __syncthreads();  // extra safety: fence store-reads of s_o vs next epilogue
    }
}

extern "C" void kernel_launch(void* const* d_in, const int* in_sizes, int n_in,
                              void* d_out, int out_size, void* d_ws, size_t ws_size,
                              hipStream_t stream) {
    const float* feats  = (const float*)d_in[0];
    const float* protos = (const float*)d_in[1];
    const float* dscale = (const float*)d_in[2];
    float* out = (float*)d_out;

    isomax_fused_diag<<<(B * H) / 4, 1024, 0, stream>>>(feats, protos, dscale, out);
}

// Round 12
// 92.098 us; speedup vs baseline: 1.2329x; 1.2329x over previous
//
#include <hip/hip_runtime.h>
#include <math.h>

// Problem dims (fixed by reference setup_inputs)
#define B 2
#define C 128
#define H 128
#define W 256
#define K 20
#define HW (H * W)

typedef float f32x4 __attribute__((ext_vector_type(4)));
typedef short bf16x8 __attribute__((ext_vector_type(8)));

__device__ __forceinline__ unsigned f2bf_bits(float x) {
    unsigned u = __float_as_uint(x);
    return (u + 0x7FFFu + ((u >> 16) & 1u)) >> 16;
}
__device__ __forceinline__ float bf_to_f(unsigned bits) {
    return __uint_as_float(bits << 16);
}

// ---------------- Kernel A: prep ----------------
// blocks 0..8191: 4 waves x 1 W-row norm each; B*C*H = 32768 rows total
//                 (R11 BUG: launched only 2048 blocks -> 3/4 of rn_ws poisoned)
// block 8192:     pnf_ws = bf16 prototypes packed in MFMA B-fragment order
//                 (R5-verified layout), ppsum_ws[k] = sum_c bf(pn[k,c])^2
__global__ __launch_bounds__(256) void isomax_prep(
    const float* __restrict__ feats, const float* __restrict__ protos,
    float* __restrict__ rn_ws, short* __restrict__ pnf_ws, float* __restrict__ ppsum_ws)
{
    const int tid = threadIdx.x, wave = tid >> 6, lane = tid & 63;
    const int blk = blockIdx.x;

    if (blk < 8192) {
        const int r = blk * 4 + wave;  // row id = (b*C + c)*H + h, 32768 rows
        const float4 v = ((const float4*)(feats + (size_t)r * W))[lane];
        float ss = fmaf(v.x, v.x, fmaf(v.y, v.y, fmaf(v.z, v.z, v.w * v.w)));
        #pragma unroll
        for (int off = 32; off > 0; off >>= 1) ss += __shfl_xor(ss, off, 64);
        if (lane == 0) {
            const int h  = r & (H - 1);
            const int bc = r >> 7;
            const int c  = bc & (C - 1);
            const int b  = bc >> 7;
            rn_ws[(b * H + h) * C + c] = 1.0f / fmaxf(sqrtf(ss), 1e-12f);
        }
    } else {
        __shared__ float s_rp[32];
        for (int k = wave; k < K; k += 4) {
            const float* p = protos + k * C;
            float a = p[lane], bq = p[lane + 64];
            float ss = fmaf(a, a, bq * bq);
            #pragma unroll
            for (int off = 32; off > 0; off >>= 1) ss += __shfl_xor(ss, off, 64);
            if (lane == 0) s_rp[k] = 1.0f / fmaxf(sqrtf(ss), 1e-12f);
        }
        __syncthreads();
        // B-fragments (R5-verified): i = [t][ch][lane][j]
        for (int i = tid; i < 4096; i += 256) {
            const int j  = i & 7;
            const int ln = (i >> 3) & 63;
            const int ch = (i >> 9) & 3;
            const int t  = i >> 11;
            const int c  = ch * 32 + ((ln >> 4) & 3) * 8 + j;
            const int k  = t * 16 + (ln & 15);
            float val = (k < K) ? protos[k * C + c] * s_rp[k] : 0.0f;
            pnf_ws[i] = (short)f2bf_bits(val);
        }
        if (tid < 32) {
            float s = 0.f;
            if (tid < K) {
                const float rp = s_rp[tid];
                for (int c = 0; c < C; ++c) {
                    float pb = bf_to_f(f2bf_bits(protos[tid * C + c] * rp));
                    s = fmaf(pb, pb, s);
                }
            }
            ppsum_ws[tid] = s;
        }
    }
}

// ---------------- Kernel B: dist (unchanged from R11) ----------------
// Grid = B*H*8 (32-w windows) = 2048 blocks; 256 thr = 4 waves.
// Wave = (mt = wave>>1 -> 16-w m-tile, chalf = wave&1 -> 64-c half).
// 8 blocks/CU = 32 waves/CU; ~8 KB LDS; A-frags gathered direct from global
// (L3-warm after prep); c-half partials combined in LDS.
#define SO_ST 36   // s_o row stride (floats): float4-aligned
__global__ __launch_bounds__(256, 8) void isomax_dist(
    const float* __restrict__ feats, const float* __restrict__ rn_ws,
    const short* __restrict__ pnf_ws, const float* __restrict__ ppsum_ws,
    const float* __restrict__ dscale, float* __restrict__ out)
{
    __shared__ float s_rn[C];
    __shared__ float s_pp[32];
    __shared__ float s_part[2][64][8];   // [mt][lane][acc0(4)|acc1(4)] from chalf=1
    __shared__ float s_Sh[2][16];        // chalf=1 half-S per (mt, l16)
    __shared__ float s_S[2 * 16];        // combined S[w-local]
    __shared__ __align__(16) float s_o[K * SO_ST];  // 2.9 KB output transpose

    const int tid  = threadIdx.x;
    const int wave = tid >> 6, lane = tid & 63;
    const int quad = lane >> 4, l16 = lane & 15;
    const int blk  = blockIdx.x;
    const int bh   = blk >> 3;
    const int oct  = blk & 7;
    const int b    = bh >> 7, h = bh & 127;
    const int w0   = oct * 32;
    const int mt   = wave >> 1;          // m-tile index (0,1)
    const int ch0  = (wave & 1) * 2;     // first 32-c chunk of this wave's c-half

    if (tid < C)  s_rn[tid] = rn_ws[bh * C + tid];
    if (tid < 32) s_pp[tid] = ppsum_ws[tid];
    __syncthreads();

    // B-fragments for this wave's two c-chunks (R5-verified indexing)
    bf16x8 bfr[2][2];
    #pragma unroll
    for (int t = 0; t < 2; ++t)
        #pragma unroll
        for (int c2 = 0; c2 < 2; ++c2)
            bfr[c2][t] = ((const bf16x8*)pnf_ws)[(t * 4 + ch0 + c2) * 64 + lane];

    // A-frags direct from global + 4 MFMAs; Sp from rounded u (consistency)
    f32x4 acc0 = {0.f, 0.f, 0.f, 0.f}, acc1 = {0.f, 0.f, 0.f, 0.f};
    float Sp = 0.f;
    const float* fbase = feats + (size_t)b * C * HW + h * W + w0 + mt * 16 + l16;
    #pragma unroll
    for (int c2 = 0; c2 < 2; ++c2) {
        const int ch = ch0 + c2;
        bf16x8 af;
        #pragma unroll
        for (int j = 0; j < 8; ++j) {
            const int c = ch * 32 + quad * 8 + j;
            const float uf = fbase[(size_t)c * HW] * s_rn[c];
            const unsigned bits = f2bf_bits(uf);
            af[j] = (short)bits;
            const float ur = bf_to_f(bits);
            Sp = fmaf(ur, ur, Sp);
        }
        acc0 = __builtin_amdgcn_mfma_f32_16x16x32_bf16(af, bfr[c2][0], acc0, 0, 0, 0);
        acc1 = __builtin_amdgcn_mfma_f32_16x16x32_bf16(af, bfr[c2][1], acc1, 0, 0, 0);
    }

    // half-c S for w = w0 + mt*16 + l16 (quad partials summed)
    Sp += __shfl_xor(Sp, 16, 64);
    Sp += __shfl_xor(Sp, 32, 64);

    // ---- combine c-halves (intra-block) ----
    if (wave & 1) {                       // chalf=1 deposits partials
        #pragma unroll
        for (int e = 0; e < 4; ++e) {
            s_part[mt][lane][e]     = acc0[e];
            s_part[mt][lane][4 + e] = acc1[e];
        }
        if (lane < 16) s_Sh[mt][lane] = Sp;
    }
    __syncthreads();
    if (!(wave & 1)) {                    // chalf=0 combines + stages S
        #pragma unroll
        for (int e = 0; e < 4; ++e) {
            acc0[e] += s_part[mt][lane][e];
            acc1[e] += s_part[mt][lane][4 + e];
        }
        const float Sfull = Sp + s_Sh[mt][l16];
        if (lane < 16) s_S[mt * 16 + lane] = Sfull;
    }
    __syncthreads();

    // ---- epilogue (chalf=0 waves), R7-style transpose through LDS ----
    if (!(wave & 1)) {
        const float scale = fabsf(dscale[0]);
        const float pcol0 = s_pp[l16];
        const float pcol1 = (l16 < 4) ? s_pp[16 + l16] : 0.0f;
        #pragma unroll
        for (int r = 0; r < 4; ++r) {
            const int wl = mt * 16 + quad * 4 + r;     // block-local w (0..31)
            const float Sm = s_S[wl];
            const float d20 = fmaxf(Sm + pcol0 - 2.0f * acc0[r], 0.f);
            s_o[l16 * SO_ST + wl] = -scale * sqrtf(d20);
            if (l16 < 4) {
                const float d21 = fmaxf(Sm + pcol1 - 2.0f * acc1[r], 0.f);
                s_o[(16 + l16) * SO_ST + wl] = -scale * sqrtf(d21);
            }
        }
    }
    __syncthreads();

    // ---- store: 20 k-rows x 32 w, float4 ----
    for (int i = tid; i < K * 8; i += 256) {
        const int k = i >> 3, g = i & 7;
        const float4 v = *(const float4*)&s_o[k * SO_ST + g * 4];
        *(float4*)(out + ((size_t)(b * K + k)) * HW + h * W + w0 + g * 4) = v;
    }
}

extern "C" void kernel_launch(void* const* d_in, const int* in_sizes, int n_in,
                              void* d_out, int out_size, void* d_ws, size_t ws_size,
                              hipStream_t stream) {
    const float* feats  = (const float*)d_in[0];
    const float* protos = (const float*)d_in[1];
    const float* dscale = (const float*)d_in[2];
    float* out = (float*)d_out;

    float* rn_ws    = (float*)d_ws;            // 32768 floats [b*H+h][c]
    float* ppsum_ws = rn_ws + 32768;           // 32 floats
    short* pnf_ws   = (short*)(ppsum_ws + 32); // 4096 bf16 fragment-packed

    isomax_prep<<<8193, 256, 0, stream>>>(feats, protos, rn_ws, pnf_ws, ppsum_ws);
    isomax_dist<<<B * H * 8, 256, 0, stream>>>(feats, rn_ws, pnf_ws, ppsum_ws,
                                               dscale, out);
}